// Round 10
// baseline (469.292 us; speedup 1.0000x reference)
//
#include <hip/hip_runtime.h>
#include <hip/hip_bf16.h>
#include <math.h>

// ---------------------------------------------------------------------------
// MultiHeadSelfAttention  B=4 N=2048 E=512 H=8 DK=DV=64   (f32 in / f32 out)
// Split-bf16 (hi/lo) MFMA on the attention-critical path (verified R3-R9,
// absmax 0.0078 vs threshold 0.0333).
//
// Reference quirks (verified passing):
//  * qkv.reshape(B,H,N,192) is token-mixing: with GEMM col g:
//    s=g/192, sect=(g%192)/64, d=g%64, n=8a+s (a=row%256, bh=row/256).
//  * y.reshape: y[b,h,n,d] -> yws[bh*256 + (n>>3)][(n&7)*64 + d]
//  * qk / DK**-0.5 == qk * 8.0
//
// R10 (R9 post-mortem: attn register-capped at 2 waves/SIMD ~230 unified
// regs; three designs all ~100-117us for this reason):
//  * attn: Q tile staged to LDS (frees 64 VGPRs), rf-outer loop (sacc 32->8),
//    no K prefetch (occupancy hides latency), __launch_bounds__(256,3) to
//    force <=170 regs -> 3 waves/SIMD. p_lds/red LDS union -> 39KB/block.
//  * attn: lsum sums raw f32 p (drop bf16 mask; +1e-3 bias, margin 4x).
//  * out_gemm: 32x128 tiles, grid 1024 (was 256 = 1 block/CU).
// ---------------------------------------------------------------------------

typedef __attribute__((ext_vector_type(8))) short bf16x8;
typedef __attribute__((ext_vector_type(4))) float f32x4;

#define MFMA16(a, b, c) __builtin_amdgcn_mfma_f32_16x16x32_bf16((a), (b), (c), 0, 0, 0)

__device__ __forceinline__ ushort f2bf_rne(float f) {
  union { float f; unsigned u; } v; v.f = f;
  return (ushort)((v.u + 0x7fffu + ((v.u >> 16) & 1u)) >> 16);
}
__device__ __forceinline__ float bf2f(ushort h) {
  union { float f; unsigned u; } v; v.u = ((unsigned)h) << 16; return v.f;
}
__device__ __forceinline__ void split2(float f, ushort& hi, ushort& lo) {
  union { float f; unsigned u; } v; v.f = f;
  hi = (ushort)(v.u >> 16);
  union { float f; unsigned u; } r; r.f = f - bf2f(hi);
  lo = (ushort)(r.u >> 16);          // trunc lo: rel err ~2^-16.5, negligible
}

// ---------------------------------------------------------------------------
// K0 (fused): W_qkv -> wT_hi/lo (1536x512 k-major); W_o -> woT; and if ROOMY,
// x -> xh/xl bf16 planes. Grid: ROOMY ? 8192 : 4096 blocks.
// ---------------------------------------------------------------------------
template <bool ROOMY>
__global__ __launch_bounds__(256) void cvt_k(const float* __restrict__ wqkv,
                                             const float* __restrict__ wo,
                                             const float* __restrict__ x,
                                             ushort* __restrict__ wT_hi,
                                             ushort* __restrict__ wT_lo,
                                             ushort* __restrict__ woT,
                                             ushort* __restrict__ xh,
                                             ushort* __restrict__ xl)
{
  const int gid = blockIdx.x * 256 + threadIdx.x;
  if (gid < 786432) {
    const int n = gid >> 9, k = gid & 511;
    ushort hi, lo; split2(wqkv[(size_t)k * 1536 + n], hi, lo);
    wT_hi[gid] = hi; wT_lo[gid] = lo;
  } else if (gid < 1048576) {
    const int g = gid - 786432;
    const int n = g >> 9, k = g & 511;
    woT[g] = f2bf_rne(wo[(size_t)k * 512 + n]);
  } else if (ROOMY) {
    const int g = gid - 1048576;        // 1048576 vec4 slots
    float4 v = ((const float4*)x)[g];
    ushort4 hh, ll;
    split2(v.x, hh.x, ll.x); split2(v.y, hh.y, ll.y);
    split2(v.z, hh.z, ll.z); split2(v.w, hh.w, ll.w);
    ((ushort4*)xh)[g] = hh;
    ((ushort4*)xl)[g] = ll;
  }
}

// ---------------------------------------------------------------------------
// K1: qkv GEMM, 128x128 tile/block (4 waves 2x2, wave = 64x64 = 4x4 acc).
// PRECVT: A frags = direct bf16x8 loads from xh/xl; else f32 + in-reg split.
// B = wT hi/lo via double-buffered LDS, 1 barrier/chunk, post-barrier
// prefetch. XCD swizzle. Coalesced epilogue via wave-private LDS transpose.
// ---------------------------------------------------------------------------
template <bool PRECVT>
__global__ __launch_bounds__(256) void qkv_gemm_k(
    const float* __restrict__ x,
    const ushort* __restrict__ xh, const ushort* __restrict__ xl,
    const ushort* __restrict__ wT_hi, const ushort* __restrict__ wT_lo,
    const float* __restrict__ bqkv,
    ushort* __restrict__ q_hi, ushort* __restrict__ q_lo,
    ushort* __restrict__ k_hi, ushort* __restrict__ k_lo,
    ushort* __restrict__ v_nat)
{
  const int i = blockIdx.x, j = i >> 3;
  const int tmb = (i & 7) * 8 + (j & 7);   // row-strip, XCD-grouped
  const int tn  = j >> 3;                  // col-panel [0,12)
  const int tid = threadIdx.x, lane = tid & 63, w = tid >> 6;
  const int col16 = lane & 15, quad = lane >> 4;
  const int wr = w >> 1, wc = w & 1;

  __shared__ short bh_lds[2][128][40];   // [n][k], 80B rows (16B-aligned)
  __shared__ short bl_lds[2][128][40];

  const int sn = tid >> 1, sk = (tid & 1) * 16;
  const ushort* bhsrc = wT_hi + (size_t)(tn * 128 + sn) * 512 + sk;
  const ushort* blsrc = wT_lo + (size_t)(tn * 128 + sn) * 512 + sk;

  const float*  axf[4];
  const ushort *axh[4], *axl[4];
#pragma unroll
  for (int rt = 0; rt < 4; ++rt) {
    const size_t rowoff = (size_t)(tmb * 128 + wr * 64 + rt * 16 + col16) * 512 + quad * 8;
    axf[rt] = x  + rowoff;
    axh[rt] = xh + rowoff;
    axl[rt] = xl + rowoff;
  }

  f32x4 acc[4][4];
#pragma unroll
  for (int rt = 0; rt < 4; ++rt)
#pragma unroll
    for (int ct = 0; ct < 4; ++ct) acc[rt][ct] = (f32x4){0.f, 0.f, 0.f, 0.f};

  uint4 rb0 = *(const uint4*)(bhsrc);
  uint4 rb1 = *(const uint4*)(bhsrc + 8);
  uint4 rb2 = *(const uint4*)(blsrc);
  uint4 rb3 = *(const uint4*)(blsrc + 8);
  *(uint4*)(&bh_lds[0][sn][sk])     = rb0;
  *(uint4*)(&bh_lds[0][sn][sk + 8]) = rb1;
  *(uint4*)(&bl_lds[0][sn][sk])     = rb2;
  *(uint4*)(&bl_lds[0][sn][sk + 8]) = rb3;

  for (int c = 0; c < 16; ++c) {
    __syncthreads();
    if (c < 15) {                       // issue next-chunk loads AFTER barrier
      const int k0 = (c + 1) * 32;
      rb0 = *(const uint4*)(bhsrc + k0);
      rb1 = *(const uint4*)(bhsrc + k0 + 8);
      rb2 = *(const uint4*)(blsrc + k0);
      rb3 = *(const uint4*)(blsrc + k0 + 8);
    }
    const int b = c & 1, k0 = c * 32;

    bf16x8 bh[4], bl[4];
#pragma unroll
    for (int ct = 0; ct < 4; ++ct) {
      bh[ct] = *(const bf16x8*)(&bh_lds[b][wc * 64 + ct * 16 + col16][quad * 8]);
      bl[ct] = *(const bf16x8*)(&bl_lds[b][wc * 64 + ct * 16 + col16][quad * 8]);
    }
#pragma unroll
    for (int rt = 0; rt < 4; ++rt) {
      bf16x8 a_hi, a_lo;
      if constexpr (PRECVT) {
        a_hi = *(const bf16x8*)(axh[rt] + k0);
        a_lo = *(const bf16x8*)(axl[rt] + k0);
      } else {
        float4 xa = *(const float4*)(axf[rt] + k0);
        float4 xb = *(const float4*)(axf[rt] + k0 + 4);
#pragma unroll
        for (int jj = 0; jj < 4; ++jj) {
          ushort h, l;
          split2(((const float*)&xa)[jj], h, l);
          ((short*)&a_hi)[jj] = (short)h; ((short*)&a_lo)[jj] = (short)l;
          split2(((const float*)&xb)[jj], h, l);
          ((short*)&a_hi)[4 + jj] = (short)h; ((short*)&a_lo)[4 + jj] = (short)l;
        }
      }
#pragma unroll
      for (int ct = 0; ct < 4; ++ct) {
        acc[rt][ct] = MFMA16(a_hi, bh[ct], acc[rt][ct]);
        acc[rt][ct] = MFMA16(a_hi, bl[ct], acc[rt][ct]);
        acc[rt][ct] = MFMA16(a_lo, bh[ct], acc[rt][ct]);
      }
    }
    if (c < 15) {                       // vmcnt wait here, overlapped above
      const int nb = b ^ 1;
      *(uint4*)(&bh_lds[nb][sn][sk])     = rb0;
      *(uint4*)(&bh_lds[nb][sn][sk + 8]) = rb1;
      *(uint4*)(&bl_lds[nb][sn][sk])     = rb2;
      *(uint4*)(&bl_lds[nb][sn][sk + 8]) = rb3;
    }
  }

  // ---- coalesced epilogue via wave-private LDS transpose ----
  short* eph = ((short*)bh_lds) + w * 1152;   // 16 rows x 72
  short* epl = ((short*)bl_lds) + w * 1152;
  const int g0   = tn * 128 + wc * 64;        // wave-uniform 64-col block
  const int sect = (g0 % 192) >> 6;           // 0=q 1=k 2=v
  const int s    = g0 / 192;                  // n & 7
  float bv[4];
#pragma unroll
  for (int ct = 0; ct < 4; ++ct) bv[ct] = bqkv[g0 + ct * 16 + col16];

#pragma unroll
  for (int rt = 0; rt < 4; ++rt) {
#pragma unroll
    for (int ct = 0; ct < 4; ++ct) {
#pragma unroll
      for (int r = 0; r < 4; ++r) {
        const float val = acc[rt][ct][r] + bv[ct];
        const int o = (quad * 4 + r) * 72 + ct * 16 + col16;
        if (sect == 2) {
          eph[o] = (short)f2bf_rne(val);
        } else {
          ushort h, l; split2(val, h, l);
          eph[o] = (short)h; epl[o] = (short)l;
        }
      }
    }
#pragma unroll
    for (int p = 0; p < 2; ++p) {
      const int row = p * 8 + (lane >> 3);
      const int dsg = (lane & 7) * 8;
      const int grow = tmb * 128 + wr * 64 + rt * 16 + row;
      const int bhh = grow >> 8, a = grow & 255;
      const size_t idx = ((size_t)bhh * 2048 + 8 * a + s) * 64 + dsg;
      uint4 hv = *(const uint4*)(eph + row * 72 + dsg);
      if (sect == 0) {
        *(uint4*)(q_hi + idx) = hv;
        uint4 lv = *(const uint4*)(epl + row * 72 + dsg);
        *(uint4*)(q_lo + idx) = lv;
      } else if (sect == 1) {
        *(uint4*)(k_hi + idx) = hv;
        uint4 lv = *(const uint4*)(epl + row * 72 + dsg);
        *(uint4*)(k_lo + idx) = lv;
      } else {
        *(uint4*)(v_nat + idx) = hv;
      }
    }
  }
}

// ---------------------------------------------------------------------------
// K1b: v [bh][n][d] -> vT [bh][d][n].  Grid: 32 bh x 8 n-tiles(256) = 256.
// ---------------------------------------------------------------------------
__global__ __launch_bounds__(256) void vtrans_k(const ushort* __restrict__ v_nat,
                                                ushort* __restrict__ vT)
{
  const int t  = blockIdx.x & 7;
  const int bh = blockIdx.x >> 3;
  const int tid = threadIdx.x;
  const int nl = tid & 63;
  const int dg = tid >> 6;
  const size_t base = (size_t)bh * 2048 * 64;
#pragma unroll
  for (int p = 0; p < 2; ++p) {
    const int dseg = dg + p * 4;
#pragma unroll
    for (int nb = 0; nb < 4; ++nb) {
      const int n = t * 256 + nb * 64 + nl;
      uint4 vv = *(const uint4*)(v_nat + base + (size_t)n * 64 + dseg * 8);
      const ushort* pv = (const ushort*)&vv;
#pragma unroll
      for (int j = 0; j < 8; ++j)
        vT[base + (size_t)(dseg * 8 + j) * 2048 + n] = pv[j];
    }
  }
}

// ---------------------------------------------------------------------------
// K2: key-partitioned barrier-free flash attention, fixed-shift softmax
// (p = 2^(s*S2-128); stats bound l<=2^71, row-max p >= ~2^-40).
// Block = 256 thr (4 waves) x 64-query tile; wave w owns key-slice
// it*128+w*32 (16 iters, additive). Grid = 1024, XCD-swizzled.
// R10: Q tile in LDS (frees 64 VGPRs), rf-outer loop (sacc 8 live), no K
// prefetch, launch_bounds(256,3) -> target 3 waves/SIMD. p_lds/red aliased.
// ---------------------------------------------------------------------------
__global__ __launch_bounds__(256, 3) void attn_k(
    const ushort* __restrict__ q_hi, const ushort* __restrict__ q_lo,
    const ushort* __restrict__ k_hi, const ushort* __restrict__ k_lo,
    const ushort* __restrict__ vT, ushort* __restrict__ y)
{
  const int i  = blockIdx.x;
  const int bh = (i & 7) * 4 + (i >> 8);     // 8 XCD groups x 4 bh
  const int qt = (i >> 3) & 31;              // 32 q-tiles of 64
  const int tid = threadIdx.x, lane = tid & 63, w = tid >> 6;
  const int col16 = lane & 15, quad = lane >> 4;

  __shared__ short qh_lds[64][72];           // Q tile hi (9.2 KB)
  __shared__ short ql_lds[64][72];           // Q tile lo
  __shared__ alignas(16) char pbuf[20480];   // p_lds | red (aliased)
  __shared__ float lred[4][16];
  auto p_lds = (short (*)[4][16][40])pbuf;   // [wave][rf][q-row][32key+pad]
  auto red   = (float (*)[16][68])pbuf;      // [wave][q-row][64d+pad]

  const unsigned base = (unsigned)bh * 131072u;
  const int qb = qt * 64;
  const ushort* khb = k_hi + base;
  const ushort* klb = k_lo + base;
  const ushort* vtb = vT  + base;

  // stage Q tile (64x64, hi+lo) to LDS, coalesced
  {
    const int row = tid >> 2, seg = (tid & 3) * 16;
    const unsigned off = base + (unsigned)(qb + row) * 64u + seg;
    *(uint4*)(&qh_lds[row][seg])     = *(const uint4*)(q_hi + off);
    *(uint4*)(&qh_lds[row][seg + 8]) = *(const uint4*)(q_hi + off + 8);
    *(uint4*)(&ql_lds[row][seg])     = *(const uint4*)(q_lo + off);
    *(uint4*)(&ql_lds[row][seg + 8]) = *(const uint4*)(q_lo + off + 8);
  }
  __syncthreads();

  f32x4 oacc[4][4];
#pragma unroll
  for (int rf = 0; rf < 4; ++rf)
#pragma unroll
    for (int ct = 0; ct < 4; ++ct) oacc[rf][ct] = (f32x4){0.f, 0.f, 0.f, 0.f};
  f32x4 lsum[4];
#pragma unroll
  for (int rf = 0; rf < 4; ++rf) lsum[rf] = (f32x4){0.f, 0.f, 0.f, 0.f};

  const float S2 = 11.541560327111707f;      // 8 * log2(e)

  for (int it = 0; it < 16; ++it) {
    const unsigned kb = (unsigned)(it * 128 + w * 32);   // wave's 32-key slice

    // V frags (B-layout for PV): issued early, consumed at PV
    bf16x8 vf[4];
#pragma unroll
    for (int ct = 0; ct < 4; ++ct)
      vf[ct] = *(const bf16x8*)(vtb + (unsigned)(ct * 16 + col16) * 2048u + kb + quad * 8);

    // K frags for this iter (2 kt x 2 ks, hi/lo) — 32 regs
    bf16x8 khf[2][2], klf[2][2];
#pragma unroll
    for (int kt = 0; kt < 2; ++kt)
#pragma unroll
      for (int ks = 0; ks < 2; ++ks) {
        const unsigned off = (kb + kt * 16 + col16) * 64u + ks * 32 + quad * 8;
        khf[kt][ks] = *(const bf16x8*)(khb + off);
        klf[kt][ks] = *(const bf16x8*)(klb + off);
      }

    // rf-outer: Q from LDS (transient), S (3-term split), softmax, P->LDS
#pragma unroll
    for (int rf = 0; rf < 4; ++rf) {
      bf16x8 qhf[2], qlf[2];
#pragma unroll
      for (int ks = 0; ks < 2; ++ks) {
        qhf[ks] = *(const bf16x8*)(&qh_lds[rf * 16 + col16][ks * 32 + quad * 8]);
        qlf[ks] = *(const bf16x8*)(&ql_lds[rf * 16 + col16][ks * 32 + quad * 8]);
      }
      f32x4 sacc[2];
      sacc[0] = (f32x4){0.f, 0.f, 0.f, 0.f};
      sacc[1] = (f32x4){0.f, 0.f, 0.f, 0.f};
#pragma unroll
      for (int kt = 0; kt < 2; ++kt)
#pragma unroll
        for (int ks = 0; ks < 2; ++ks) {
          sacc[kt] = MFMA16(qhf[ks], khf[kt][ks], sacc[kt]);
          sacc[kt] = MFMA16(qhf[ks], klf[kt][ks], sacc[kt]);
          sacc[kt] = MFMA16(qlf[ks], khf[kt][ks], sacc[kt]);
        }
#pragma unroll
      for (int kt = 0; kt < 2; ++kt)
#pragma unroll
        for (int r = 0; r < 4; ++r) {
          const float p = __builtin_amdgcn_exp2f(fmaf(sacc[kt][r], S2, -128.0f));
          lsum[rf][r] += p;              // raw f32 (tiny bias vs bf16-P, ok)
          union { float f; unsigned u; } pu; pu.f = p;
          p_lds[w][rf][quad * 4 + r][kt * 16 + col16] = (short)(pu.u >> 16);
        }
    }

    // PV: O += P V over this wave's 32 keys (A = P roundtrip, K=32)
#pragma unroll
    for (int rf = 0; rf < 4; ++rf) {
      bf16x8 apf = *(const bf16x8*)(&p_lds[w][rf][col16][quad * 8]);
#pragma unroll
      for (int ct = 0; ct < 4; ++ct)
        oacc[rf][ct] = MFMA16(apf, vf[ct], oacc[rf][ct]);
    }
  }

  // ---- cross-wave additive reduction of O and l, then store (4 rf passes)
  // red aliases p_lds: barrier before EVERY pass (incl. first) since other
  // waves may still be reading their p_lds region.
#pragma unroll
  for (int rf = 0; rf < 4; ++rf) {
    __syncthreads();
    float lrow[4];
#pragma unroll
    for (int r = 0; r < 4; ++r) {
      float l = lsum[rf][r];
#pragma unroll
      for (int off = 1; off < 16; off <<= 1) l += __shfl_xor(l, off, 64);
      lrow[r] = l;
    }
    if (col16 == 0) {
#pragma unroll
      for (int r = 0; r < 4; ++r) lred[w][quad * 4 + r] = lrow[r];
    }
#pragma unroll
    for (int ct = 0; ct < 4; ++ct)
#pragma unroll
      for (int r = 0; r < 4; ++r)
        red[w][quad * 4 + r][ct * 16 + col16] = oacc[rf][ct][r];
    __syncthreads();

    const int row = tid >> 4, db = (tid & 15) * 4;
    f32x4 s = (f32x4){0.f, 0.f, 0.f, 0.f};
    float l = 0.f;
#pragma unroll
    for (int ww = 0; ww < 4; ++ww) {
      const f32x4 t = *(const f32x4*)(&red[ww][row][db]);
      s += t;
      l += lred[ww][row];
    }
    const float inv = 1.f / l;
    const int n = qb + rf * 16 + row;
    const size_t orow = ((size_t)bh * 256 + (n >> 3)) * 512 + (n & 7) * 64 + db;
    ushort4 o4;
    o4.x = f2bf_rne(s[0] * inv); o4.y = f2bf_rne(s[1] * inv);
    o4.z = f2bf_rne(s[2] * inv); o4.w = f2bf_rne(s[3] * inv);
    *(ushort4*)(y + orow) = o4;
  }
}

// ---------------------------------------------------------------------------
// K3: out = y @ Wo + bo, 32x128 tiles (plain bf16 MFMA, f32 out). Grid 1024
// (4 blocks/CU), XCD-swizzled. Wave = 16 rows x 64 cols. Double-buffered B.
// ---------------------------------------------------------------------------
__global__ __launch_bounds__(256) void out_gemm_k(
    const ushort* __restrict__ y, const ushort* __restrict__ woT,
    const float* __restrict__ bo, float* __restrict__ out)
{
  const int i = blockIdx.x, j = i >> 3;
  const int tmb = (i & 7) * 32 + (j & 31);  // 256 row-strips of 32, XCD-grouped
  const int tn  = j >> 5;                   // [0,4) col-panel of 128
  const int tid = threadIdx.x, lane = tid & 63, w = tid >> 6;
  const int col16 = lane & 15, quad = lane >> 4;
  const int wr = w >> 1, wc = w & 1;

  __shared__ short b_lds[2][128][40];

  const int sn = tid >> 1, sk = (tid & 1) * 16;
  const ushort* bsrc = woT + (size_t)(tn * 128 + sn) * 512 + sk;

  const ushort* ay = y + (size_t)(tmb * 32 + wr * 16 + col16) * 512 + quad * 8;

  f32x4 acc[4];
#pragma unroll
  for (int ct = 0; ct < 4; ++ct) acc[ct] = (f32x4){0.f, 0.f, 0.f, 0.f};

  uint4 rb0 = *(const uint4*)(bsrc);
  uint4 rb1 = *(const uint4*)(bsrc + 8);
  *(uint4*)(&b_lds[0][sn][sk])     = rb0;
  *(uint4*)(&b_lds[0][sn][sk + 8]) = rb1;

  for (int c = 0; c < 16; ++c) {
    __syncthreads();
    if (c < 15) {
      const int k0 = (c + 1) * 32;
      rb0 = *(const uint4*)(bsrc + k0);
      rb1 = *(const uint4*)(bsrc + k0 + 8);
    }
    const int b = c & 1, k0 = c * 32;
    bf16x8 af = *(const bf16x8*)(ay + k0);
#pragma unroll
    for (int ct = 0; ct < 4; ++ct) {
      bf16x8 bfr = *(const bf16x8*)(&b_lds[b][wc * 64 + ct * 16 + col16][quad * 8]);
      acc[ct] = MFMA16(af, bfr, acc[ct]);
    }
    if (c < 15) {
      const int nb = b ^ 1;
      *(uint4*)(&b_lds[nb][sn][sk])     = rb0;
      *(uint4*)(&b_lds[nb][sn][sk + 8]) = rb1;
    }
  }
#pragma unroll
  for (int ct = 0; ct < 4; ++ct) {
    const int col = tn * 128 + wc * 64 + ct * 16 + col16;
    const float bval = bo[col];
#pragma unroll
    for (int r = 0; r < 4; ++r) {
      const int row = tmb * 32 + wr * 16 + quad * 4 + r;
      out[(size_t)row * 512 + col] = acc[ct][r] + bval;
    }
  }
}

// ---------------------------------------------------------------------------
extern "C" void kernel_launch(void* const* d_in, const int* in_sizes, int n_in,
                              void* d_out, int out_size, void* d_ws, size_t ws_size,
                              hipStream_t stream)
{
  const float* x    = (const float*)d_in[0];
  const float* Wqkv = (const float*)d_in[1];
  const float* bqkv = (const float*)d_in[2];
  const float* Wo   = (const float*)d_in[3];
  const float* bo   = (const float*)d_in[4];
  float* out = (float*)d_out;

  // ws (ushort elems). Base (R6-proven, 54.0 MB): weights + q/k/v planes.
  ushort* wT_hi = (ushort*)d_ws;                    //  786432
  ushort* wT_lo = wT_hi + 786432;                   //  786432
  ushort* woT   = wT_lo + 786432;                   //  262144
  ushort* q_hi  = woT   + 262144;                   // 4194304 each below
  ushort* q_lo  = q_hi  + 4194304;
  ushort* k_hi  = q_lo  + 4194304;
  ushort* k_lo  = k_hi  + 4194304;
  ushort* v_nat = k_lo  + 4194304;
  ushort* tail  = v_nat + 4194304;

  // Roomy path (62.4 MB): xh/xl planes; vT aliases xh, y aliases xl (both
  // dead after K1). ws_size is launch-invariant -> stable graph capture.
  const bool roomy = ws_size >= 62390272ULL;
  ushort *xh, *xl, *vT, *y;
  if (roomy) {
    xh = tail; xl = tail + 4194304;
    vT = xh;   y  = xl;                 // reused post-K1
  } else {
    xh = xl = nullptr;
    vT = tail; y = v_nat;               // R6 mapping (54.0 MB, proven)
  }

  if (roomy) {
    cvt_k<true><<<8192, 256, 0, stream>>>(Wqkv, Wo, x, wT_hi, wT_lo, woT, xh, xl);
    qkv_gemm_k<true><<<768, 256, 0, stream>>>(x, xh, xl, wT_hi, wT_lo, bqkv,
                                              q_hi, q_lo, k_hi, k_lo, v_nat);
  } else {
    cvt_k<false><<<4096, 256, 0, stream>>>(Wqkv, Wo, x, wT_hi, wT_lo, woT,
                                           nullptr, nullptr);
    qkv_gemm_k<false><<<768, 256, 0, stream>>>(x, nullptr, nullptr, wT_hi, wT_lo,
                                               bqkv, q_hi, q_lo, k_hi, k_lo, v_nat);
  }
  vtrans_k<<<256, 256, 0, stream>>>(v_nat, vT);
  attn_k<<<1024, 256, 0, stream>>>(q_hi, q_lo, k_hi, k_lo, vT, y);
  out_gemm_k<<<1024, 256, 0, stream>>>(y, woT, bo, out);
}

// Round 11
// 253.677 us; speedup vs baseline: 1.8500x; 1.8500x over previous
//
#include <hip/hip_runtime.h>
#include <hip/hip_bf16.h>
#include <math.h>

// ---------------------------------------------------------------------------
// MultiHeadSelfAttention  B=4 N=2048 E=512 H=8 DK=DV=64   (f32 in / f32 out)
// Split-bf16 (hi/lo) MFMA on the attention-critical path (verified R3-R10,
// absmax 0.0078 vs threshold 0.0333).
//
// Reference quirks (verified passing):
//  * qkv.reshape(B,H,N,192) is token-mixing: with GEMM col g:
//    s=g/192, sect=(g%192)/64, d=g%64, n=8a+s (a=row%256, bh=row/256).
//  * y.reshape: y[b,h,n,d] -> yws[bh*256 + (n>>3)][(n&7)*64 + d]
//  * qk / DK**-0.5 == qk * 8.0
//
// R11 (R10 post-mortem: launch_bounds(256,3) forced VGPR 84 -> scratch
// spills, FETCH 20->368MB, attn 326us. Register footprint is irreducible at
// this tile shape; 2 waves/SIMD is the correct operating point):
//  * attn: RESTORED R7's empirically-best kernel (100us proven): 128-q tile,
//    cooperative double-buffered K/V LDS staging, post-barrier prefetch,
//    fixed-shift softmax, launch_bounds(256,2), grid 512. Single change:
//    exp2f -> __builtin_amdgcn_exp2f (R9 showed ocml exp2 costs VALU).
//  * keep R10's out_gemm 32x128 re-tile (non-attn time 172->143us).
//  * keep R9's fused cvt + R7's qkv_gemm/vtrans.
// ---------------------------------------------------------------------------

typedef __attribute__((ext_vector_type(8))) short bf16x8;
typedef __attribute__((ext_vector_type(4))) float f32x4;

#define MFMA16(a, b, c) __builtin_amdgcn_mfma_f32_16x16x32_bf16((a), (b), (c), 0, 0, 0)

__device__ __forceinline__ ushort f2bf_rne(float f) {
  union { float f; unsigned u; } v; v.f = f;
  return (ushort)((v.u + 0x7fffu + ((v.u >> 16) & 1u)) >> 16);
}
__device__ __forceinline__ float bf2f(ushort h) {
  union { float f; unsigned u; } v; v.u = ((unsigned)h) << 16; return v.f;
}
__device__ __forceinline__ void split2(float f, ushort& hi, ushort& lo) {
  union { float f; unsigned u; } v; v.f = f;
  hi = (ushort)(v.u >> 16);
  union { float f; unsigned u; } r; r.f = f - bf2f(hi);
  lo = (ushort)(r.u >> 16);          // trunc lo: rel err ~2^-16.5, negligible
}

// ---------------------------------------------------------------------------
// K0 (fused): W_qkv -> wT_hi/lo (1536x512 k-major); W_o -> woT; and if ROOMY,
// x -> xh/xl bf16 planes. Grid: ROOMY ? 8192 : 4096 blocks.
// ---------------------------------------------------------------------------
template <bool ROOMY>
__global__ __launch_bounds__(256) void cvt_k(const float* __restrict__ wqkv,
                                             const float* __restrict__ wo,
                                             const float* __restrict__ x,
                                             ushort* __restrict__ wT_hi,
                                             ushort* __restrict__ wT_lo,
                                             ushort* __restrict__ woT,
                                             ushort* __restrict__ xh,
                                             ushort* __restrict__ xl)
{
  const int gid = blockIdx.x * 256 + threadIdx.x;
  if (gid < 786432) {
    const int n = gid >> 9, k = gid & 511;
    ushort hi, lo; split2(wqkv[(size_t)k * 1536 + n], hi, lo);
    wT_hi[gid] = hi; wT_lo[gid] = lo;
  } else if (gid < 1048576) {
    const int g = gid - 786432;
    const int n = g >> 9, k = g & 511;
    woT[g] = f2bf_rne(wo[(size_t)k * 512 + n]);
  } else if (ROOMY) {
    const int g = gid - 1048576;        // 1048576 vec4 slots
    float4 v = ((const float4*)x)[g];
    ushort4 hh, ll;
    split2(v.x, hh.x, ll.x); split2(v.y, hh.y, ll.y);
    split2(v.z, hh.z, ll.z); split2(v.w, hh.w, ll.w);
    ((ushort4*)xh)[g] = hh;
    ((ushort4*)xl)[g] = ll;
  }
}

// ---------------------------------------------------------------------------
// K1: qkv GEMM, 128x128 tile/block (4 waves 2x2, wave = 64x64 = 4x4 acc).
// PRECVT: A frags = direct bf16x8 loads from xh/xl; else f32 + in-reg split.
// B = wT hi/lo via double-buffered LDS, 1 barrier/chunk, post-barrier
// prefetch. XCD swizzle. Coalesced epilogue via wave-private LDS transpose.
// ---------------------------------------------------------------------------
template <bool PRECVT>
__global__ __launch_bounds__(256) void qkv_gemm_k(
    const float* __restrict__ x,
    const ushort* __restrict__ xh, const ushort* __restrict__ xl,
    const ushort* __restrict__ wT_hi, const ushort* __restrict__ wT_lo,
    const float* __restrict__ bqkv,
    ushort* __restrict__ q_hi, ushort* __restrict__ q_lo,
    ushort* __restrict__ k_hi, ushort* __restrict__ k_lo,
    ushort* __restrict__ v_nat)
{
  const int i = blockIdx.x, j = i >> 3;
  const int tmb = (i & 7) * 8 + (j & 7);   // row-strip, XCD-grouped
  const int tn  = j >> 3;                  // col-panel [0,12)
  const int tid = threadIdx.x, lane = tid & 63, w = tid >> 6;
  const int col16 = lane & 15, quad = lane >> 4;
  const int wr = w >> 1, wc = w & 1;

  __shared__ short bh_lds[2][128][40];   // [n][k], 80B rows (16B-aligned)
  __shared__ short bl_lds[2][128][40];

  const int sn = tid >> 1, sk = (tid & 1) * 16;
  const ushort* bhsrc = wT_hi + (size_t)(tn * 128 + sn) * 512 + sk;
  const ushort* blsrc = wT_lo + (size_t)(tn * 128 + sn) * 512 + sk;

  const float*  axf[4];
  const ushort *axh[4], *axl[4];
#pragma unroll
  for (int rt = 0; rt < 4; ++rt) {
    const size_t rowoff = (size_t)(tmb * 128 + wr * 64 + rt * 16 + col16) * 512 + quad * 8;
    axf[rt] = x  + rowoff;
    axh[rt] = xh + rowoff;
    axl[rt] = xl + rowoff;
  }

  f32x4 acc[4][4];
#pragma unroll
  for (int rt = 0; rt < 4; ++rt)
#pragma unroll
    for (int ct = 0; ct < 4; ++ct) acc[rt][ct] = (f32x4){0.f, 0.f, 0.f, 0.f};

  uint4 rb0 = *(const uint4*)(bhsrc);
  uint4 rb1 = *(const uint4*)(bhsrc + 8);
  uint4 rb2 = *(const uint4*)(blsrc);
  uint4 rb3 = *(const uint4*)(blsrc + 8);
  *(uint4*)(&bh_lds[0][sn][sk])     = rb0;
  *(uint4*)(&bh_lds[0][sn][sk + 8]) = rb1;
  *(uint4*)(&bl_lds[0][sn][sk])     = rb2;
  *(uint4*)(&bl_lds[0][sn][sk + 8]) = rb3;

  for (int c = 0; c < 16; ++c) {
    __syncthreads();
    if (c < 15) {                       // issue next-chunk loads AFTER barrier
      const int k0 = (c + 1) * 32;
      rb0 = *(const uint4*)(bhsrc + k0);
      rb1 = *(const uint4*)(bhsrc + k0 + 8);
      rb2 = *(const uint4*)(blsrc + k0);
      rb3 = *(const uint4*)(blsrc + k0 + 8);
    }
    const int b = c & 1, k0 = c * 32;

    bf16x8 bh[4], bl[4];
#pragma unroll
    for (int ct = 0; ct < 4; ++ct) {
      bh[ct] = *(const bf16x8*)(&bh_lds[b][wc * 64 + ct * 16 + col16][quad * 8]);
      bl[ct] = *(const bf16x8*)(&bl_lds[b][wc * 64 + ct * 16 + col16][quad * 8]);
    }
#pragma unroll
    for (int rt = 0; rt < 4; ++rt) {
      bf16x8 a_hi, a_lo;
      if constexpr (PRECVT) {
        a_hi = *(const bf16x8*)(axh[rt] + k0);
        a_lo = *(const bf16x8*)(axl[rt] + k0);
      } else {
        float4 xa = *(const float4*)(axf[rt] + k0);
        float4 xb = *(const float4*)(axf[rt] + k0 + 4);
#pragma unroll
        for (int jj = 0; jj < 4; ++jj) {
          ushort h, l;
          split2(((const float*)&xa)[jj], h, l);
          ((short*)&a_hi)[jj] = (short)h; ((short*)&a_lo)[jj] = (short)l;
          split2(((const float*)&xb)[jj], h, l);
          ((short*)&a_hi)[4 + jj] = (short)h; ((short*)&a_lo)[4 + jj] = (short)l;
        }
      }
#pragma unroll
      for (int ct = 0; ct < 4; ++ct) {
        acc[rt][ct] = MFMA16(a_hi, bh[ct], acc[rt][ct]);
        acc[rt][ct] = MFMA16(a_hi, bl[ct], acc[rt][ct]);
        acc[rt][ct] = MFMA16(a_lo, bh[ct], acc[rt][ct]);
      }
    }
    if (c < 15) {                       // vmcnt wait here, overlapped above
      const int nb = b ^ 1;
      *(uint4*)(&bh_lds[nb][sn][sk])     = rb0;
      *(uint4*)(&bh_lds[nb][sn][sk + 8]) = rb1;
      *(uint4*)(&bl_lds[nb][sn][sk])     = rb2;
      *(uint4*)(&bl_lds[nb][sn][sk + 8]) = rb3;
    }
  }

  // ---- coalesced epilogue via wave-private LDS transpose ----
  short* eph = ((short*)bh_lds) + w * 1152;   // 16 rows x 72
  short* epl = ((short*)bl_lds) + w * 1152;
  const int g0   = tn * 128 + wc * 64;        // wave-uniform 64-col block
  const int sect = (g0 % 192) >> 6;           // 0=q 1=k 2=v
  const int s    = g0 / 192;                  // n & 7
  float bv[4];
#pragma unroll
  for (int ct = 0; ct < 4; ++ct) bv[ct] = bqkv[g0 + ct * 16 + col16];

#pragma unroll
  for (int rt = 0; rt < 4; ++rt) {
#pragma unroll
    for (int ct = 0; ct < 4; ++ct) {
#pragma unroll
      for (int r = 0; r < 4; ++r) {
        const float val = acc[rt][ct][r] + bv[ct];
        const int o = (quad * 4 + r) * 72 + ct * 16 + col16;
        if (sect == 2) {
          eph[o] = (short)f2bf_rne(val);
        } else {
          ushort h, l; split2(val, h, l);
          eph[o] = (short)h; epl[o] = (short)l;
        }
      }
    }
#pragma unroll
    for (int p = 0; p < 2; ++p) {
      const int row = p * 8 + (lane >> 3);
      const int dsg = (lane & 7) * 8;
      const int grow = tmb * 128 + wr * 64 + rt * 16 + row;
      const int bhh = grow >> 8, a = grow & 255;
      const size_t idx = ((size_t)bhh * 2048 + 8 * a + s) * 64 + dsg;
      uint4 hv = *(const uint4*)(eph + row * 72 + dsg);
      if (sect == 0) {
        *(uint4*)(q_hi + idx) = hv;
        uint4 lv = *(const uint4*)(epl + row * 72 + dsg);
        *(uint4*)(q_lo + idx) = lv;
      } else if (sect == 1) {
        *(uint4*)(k_hi + idx) = hv;
        uint4 lv = *(const uint4*)(epl + row * 72 + dsg);
        *(uint4*)(k_lo + idx) = lv;
      } else {
        *(uint4*)(v_nat + idx) = hv;
      }
    }
  }
}

// ---------------------------------------------------------------------------
// K1b: v [bh][n][d] -> vT [bh][d][n].  Grid: 32 bh x 8 n-tiles(256) = 256.
// ---------------------------------------------------------------------------
__global__ __launch_bounds__(256) void vtrans_k(const ushort* __restrict__ v_nat,
                                                ushort* __restrict__ vT)
{
  const int t  = blockIdx.x & 7;
  const int bh = blockIdx.x >> 3;
  const int tid = threadIdx.x;
  const int nl = tid & 63;
  const int dg = tid >> 6;
  const size_t base = (size_t)bh * 2048 * 64;
#pragma unroll
  for (int p = 0; p < 2; ++p) {
    const int dseg = dg + p * 4;
#pragma unroll
    for (int nb = 0; nb < 4; ++nb) {
      const int n = t * 256 + nb * 64 + nl;
      uint4 vv = *(const uint4*)(v_nat + base + (size_t)n * 64 + dseg * 8);
      const ushort* pv = (const ushort*)&vv;
#pragma unroll
      for (int j = 0; j < 8; ++j)
        vT[base + (size_t)(dseg * 8 + j) * 2048 + n] = pv[j];
    }
  }
}

// ---------------------------------------------------------------------------
// K2: flash attention — R7's proven-best kernel (100us). Block = 256 thr
// (4 waves), 128-query tile (wave = 32 q as 2 row-frags). Grid = 512,
// XCD-swizzled. Fixed-shift softmax (p = 2^(s*S2-128); stats bound l<=2^71,
// row-max p >= ~2^-40). Double-buffered LDS K/V staging, 1 barrier/chunk,
// post-barrier prefetch. Only change vs R7: builtin exp2.
// ---------------------------------------------------------------------------
__global__ __launch_bounds__(256, 2) void attn_k(
    const ushort* __restrict__ q_hi, const ushort* __restrict__ q_lo,
    const ushort* __restrict__ k_hi, const ushort* __restrict__ k_lo,
    const ushort* __restrict__ vT, ushort* __restrict__ y)
{
  const int i  = blockIdx.x;
  const int bh = (i & 7) * 4 + (i >> 7);   // XCD-local bh group
  const int qt = (i >> 3) & 15;
  const int tid = threadIdx.x, lane = tid & 63, w = tid >> 6;
  const int col16 = lane & 15, quad = lane >> 4;

  __shared__ short kh_lds[2][64][72], kl_lds[2][64][72], vt_lds[2][64][72]; // 55.3 KB
  __shared__ short p_lds[4][2][16][72];                                     // 18.4 KB

  const size_t base = (size_t)bh * 2048 * 64;
  const int qw = qt * 128 + w * 32;

  bf16x8 qh[2][2], ql[2][2];
#pragma unroll
  for (int rf = 0; rf < 2; ++rf)
#pragma unroll
    for (int ks = 0; ks < 2; ++ks) {
      const size_t off = base + (size_t)(qw + rf * 16 + col16) * 64 + ks * 32 + quad * 8;
      qh[rf][ks] = *(const bf16x8*)(q_hi + off);
      ql[rf][ks] = *(const bf16x8*)(q_lo + off);
    }

  f32x4 oacc[2][4];
#pragma unroll
  for (int rf = 0; rf < 2; ++rf)
#pragma unroll
    for (int ct = 0; ct < 4; ++ct) oacc[rf][ct] = (f32x4){0.f, 0.f, 0.f, 0.f};
  f32x4 lsum[2] = {(f32x4){0.f, 0.f, 0.f, 0.f}, (f32x4){0.f, 0.f, 0.f, 0.f}};

  const int sn = tid >> 2, sd = (tid & 3) * 16;
  const ushort* khsrc = k_hi + base + (size_t)sn * 64 + sd;
  const ushort* klsrc = k_lo + base + (size_t)sn * 64 + sd;
  const ushort* vtsrc = vT  + base + (size_t)sn * 2048 + sd;

  const float S2 = 11.541560327111707f;   // 8 * log2(e)

  uint4 r0 = *(const uint4*)(khsrc);
  uint4 r1 = *(const uint4*)(khsrc + 8);
  uint4 r2 = *(const uint4*)(klsrc);
  uint4 r3 = *(const uint4*)(klsrc + 8);
  uint4 r4 = *(const uint4*)(vtsrc);
  uint4 r5 = *(const uint4*)(vtsrc + 8);
  *(uint4*)(&kh_lds[0][sn][sd])     = r0;
  *(uint4*)(&kh_lds[0][sn][sd + 8]) = r1;
  *(uint4*)(&kl_lds[0][sn][sd])     = r2;
  *(uint4*)(&kl_lds[0][sn][sd + 8]) = r3;
  *(uint4*)(&vt_lds[0][sn][sd])     = r4;
  *(uint4*)(&vt_lds[0][sn][sd + 8]) = r5;

  for (int c = 0; c < 32; ++c) {
    __syncthreads();
    if (c < 31) {                       // issue next-chunk loads AFTER barrier
      const size_t ko = (size_t)(c + 1) * 4096;
      r0 = *(const uint4*)(khsrc + ko);
      r1 = *(const uint4*)(khsrc + ko + 8);
      r2 = *(const uint4*)(klsrc + ko);
      r3 = *(const uint4*)(klsrc + ko + 8);
      r4 = *(const uint4*)(vtsrc + (c + 1) * 64);
      r5 = *(const uint4*)(vtsrc + (c + 1) * 64 + 8);
    }
    const int b = c & 1;

    f32x4 sacc[2][4];
#pragma unroll
    for (int rf = 0; rf < 2; ++rf)
#pragma unroll
      for (int ct = 0; ct < 4; ++ct) sacc[rf][ct] = (f32x4){0.f, 0.f, 0.f, 0.f};
#pragma unroll
    for (int ks = 0; ks < 2; ++ks) {
#pragma unroll
      for (int ct = 0; ct < 4; ++ct) {
        bf16x8 khf = *(const bf16x8*)(&kh_lds[b][ct * 16 + col16][ks * 32 + quad * 8]);
        bf16x8 klf = *(const bf16x8*)(&kl_lds[b][ct * 16 + col16][ks * 32 + quad * 8]);
#pragma unroll
        for (int rf = 0; rf < 2; ++rf) {
          sacc[rf][ct] = MFMA16(qh[rf][ks], khf, sacc[rf][ct]);
          sacc[rf][ct] = MFMA16(qh[rf][ks], klf, sacc[rf][ct]);
          sacc[rf][ct] = MFMA16(ql[rf][ks], khf, sacc[rf][ct]);
        }
      }
    }

    // fixed-shift softmax: p = 2^(s*S2 - 128); no max/alpha, no reductions
#pragma unroll
    for (int rf = 0; rf < 2; ++rf) {
#pragma unroll
      for (int ct = 0; ct < 4; ++ct) {
#pragma unroll
        for (int r = 0; r < 4; ++r) {
          const float p = __builtin_amdgcn_exp2f(fmaf(sacc[rf][ct][r], S2, -128.0f));
          union { float f; unsigned u; } pu; pu.f = p;
          union { unsigned u; float f; } pb; pb.u = pu.u & 0xffff0000u;
          lsum[rf][r] += pb.f;          // denominator == bf16 P the MFMA sees
          p_lds[w][rf][quad * 4 + r][ct * 16 + col16] = (short)(pu.u >> 16);
        }
      }
    }

    // O += P V ; A = P (wave-private LDS), B = V^T frags (shared LDS)
#pragma unroll
    for (int ks = 0; ks < 2; ++ks) {
#pragma unroll
      for (int ct = 0; ct < 4; ++ct) {
        bf16x8 vv = *(const bf16x8*)(&vt_lds[b][ct * 16 + col16][ks * 32 + quad * 8]);
#pragma unroll
        for (int rf = 0; rf < 2; ++rf) {
          bf16x8 ap = *(const bf16x8*)(&p_lds[w][rf][col16][ks * 32 + quad * 8]);
          oacc[rf][ct] = MFMA16(ap, vv, oacc[rf][ct]);
        }
      }
    }

    if (c < 31) {                       // vmcnt wait here, overlapped above
      const int nb = b ^ 1;
      *(uint4*)(&kh_lds[nb][sn][sd])     = r0;
      *(uint4*)(&kh_lds[nb][sn][sd + 8]) = r1;
      *(uint4*)(&kl_lds[nb][sn][sd])     = r2;
      *(uint4*)(&kl_lds[nb][sn][sd + 8]) = r3;
      *(uint4*)(&vt_lds[nb][sn][sd])     = r4;
      *(uint4*)(&vt_lds[nb][sn][sd + 8]) = r5;
    }
  }

  // epilogue: reduce l across the 16 lanes of each row, then store
#pragma unroll
  for (int rf = 0; rf < 2; ++rf) {
#pragma unroll
    for (int r = 0; r < 4; ++r) {
      float l = lsum[rf][r];
#pragma unroll
      for (int off = 1; off < 16; off <<= 1) l += __shfl_xor(l, off, 64);
      const float inv = 1.f / l;
      const int n = qw + rf * 16 + quad * 4 + r;
      const size_t orow = ((size_t)bh * 256 + (n >> 3)) * 512 + (n & 7) * 64;
#pragma unroll
      for (int ct = 0; ct < 4; ++ct)
        y[orow + ct * 16 + col16] = f2bf_rne(oacc[rf][ct][r] * inv);
    }
  }
}

// ---------------------------------------------------------------------------
// K3: out = y @ Wo + bo, 32x128 tiles (plain bf16 MFMA, f32 out). Grid 1024
// (4 blocks/CU), XCD-swizzled. Wave = 16 rows x 64 cols. Double-buffered B.
// ---------------------------------------------------------------------------
__global__ __launch_bounds__(256) void out_gemm_k(
    const ushort* __restrict__ y, const ushort* __restrict__ woT,
    const float* __restrict__ bo, float* __restrict__ out)
{
  const int i = blockIdx.x, j = i >> 3;
  const int tmb = (i & 7) * 32 + (j & 31);  // 256 row-strips of 32, XCD-grouped
  const int tn  = j >> 5;                   // [0,4) col-panel of 128
  const int tid = threadIdx.x, lane = tid & 63, w = tid >> 6;
  const int col16 = lane & 15, quad = lane >> 4;
  const int wr = w >> 1, wc = w & 1;

  __shared__ short b_lds[2][128][40];

  const int sn = tid >> 1, sk = (tid & 1) * 16;
  const ushort* bsrc = woT + (size_t)(tn * 128 + sn) * 512 + sk;

  const ushort* ay = y + (size_t)(tmb * 32 + wr * 16 + col16) * 512 + quad * 8;

  f32x4 acc[4];
#pragma unroll
  for (int ct = 0; ct < 4; ++ct) acc[ct] = (f32x4){0.f, 0.f, 0.f, 0.f};

  uint4 rb0 = *(const uint4*)(bsrc);
  uint4 rb1 = *(const uint4*)(bsrc + 8);
  *(uint4*)(&b_lds[0][sn][sk])     = rb0;
  *(uint4*)(&b_lds[0][sn][sk + 8]) = rb1;

  for (int c = 0; c < 16; ++c) {
    __syncthreads();
    if (c < 15) {
      const int k0 = (c + 1) * 32;
      rb0 = *(const uint4*)(bsrc + k0);
      rb1 = *(const uint4*)(bsrc + k0 + 8);
    }
    const int b = c & 1, k0 = c * 32;
    bf16x8 af = *(const bf16x8*)(ay + k0);
#pragma unroll
    for (int ct = 0; ct < 4; ++ct) {
      bf16x8 bfr = *(const bf16x8*)(&b_lds[b][wc * 64 + ct * 16 + col16][quad * 8]);
      acc[ct] = MFMA16(af, bfr, acc[ct]);
    }
    if (c < 15) {
      const int nb = b ^ 1;
      *(uint4*)(&b_lds[nb][sn][sk])     = rb0;
      *(uint4*)(&b_lds[nb][sn][sk + 8]) = rb1;
    }
  }
#pragma unroll
  for (int ct = 0; ct < 4; ++ct) {
    const int col = tn * 128 + wc * 64 + ct * 16 + col16;
    const float bval = bo[col];
#pragma unroll
    for (int r = 0; r < 4; ++r) {
      const int row = tmb * 32 + wr * 16 + quad * 4 + r;
      out[(size_t)row * 512 + col] = acc[ct][r] + bval;
    }
  }
}

// ---------------------------------------------------------------------------
extern "C" void kernel_launch(void* const* d_in, const int* in_sizes, int n_in,
                              void* d_out, int out_size, void* d_ws, size_t ws_size,
                              hipStream_t stream)
{
  const float* x    = (const float*)d_in[0];
  const float* Wqkv = (const float*)d_in[1];
  const float* bqkv = (const float*)d_in[2];
  const float* Wo   = (const float*)d_in[3];
  const float* bo   = (const float*)d_in[4];
  float* out = (float*)d_out;

  // ws (ushort elems). Base (R6-proven, 54.0 MB): weights + q/k/v planes.
  ushort* wT_hi = (ushort*)d_ws;                    //  786432
  ushort* wT_lo = wT_hi + 786432;                   //  786432
  ushort* woT   = wT_lo + 786432;                   //  262144
  ushort* q_hi  = woT   + 262144;                   // 4194304 each below
  ushort* q_lo  = q_hi  + 4194304;
  ushort* k_hi  = q_lo  + 4194304;
  ushort* k_lo  = k_hi  + 4194304;
  ushort* v_nat = k_lo  + 4194304;
  ushort* tail  = v_nat + 4194304;

  // Roomy path (62.4 MB): xh/xl planes; vT aliases xh, y aliases xl (both
  // dead after K1). ws_size is launch-invariant -> stable graph capture.
  const bool roomy = ws_size >= 62390272ULL;
  ushort *xh, *xl, *vT, *y;
  if (roomy) {
    xh = tail; xl = tail + 4194304;
    vT = xh;   y  = xl;                 // reused post-K1
  } else {
    xh = xl = nullptr;
    vT = tail; y = v_nat;               // R6 mapping (54.0 MB, proven)
  }

  if (roomy) {
    cvt_k<true><<<8192, 256, 0, stream>>>(Wqkv, Wo, x, wT_hi, wT_lo, woT, xh, xl);
    qkv_gemm_k<true><<<768, 256, 0, stream>>>(x, xh, xl, wT_hi, wT_lo, bqkv,
                                              q_hi, q_lo, k_hi, k_lo, v_nat);
  } else {
    cvt_k<false><<<4096, 256, 0, stream>>>(Wqkv, Wo, x, wT_hi, wT_lo, woT,
                                           nullptr, nullptr);
    qkv_gemm_k<false><<<768, 256, 0, stream>>>(x, nullptr, nullptr, wT_hi, wT_lo,
                                               bqkv, q_hi, q_lo, k_hi, k_lo, v_nat);
  }
  vtrans_k<<<256, 256, 0, stream>>>(v_nat, vT);
  attn_k<<<512, 256, 0, stream>>>(q_hi, q_lo, k_hi, k_lo, vT, y);
  out_gemm_k<<<1024, 256, 0, stream>>>(y, woT, bo, out);
}